// Round 3
// baseline (155.290 us; speedup 1.0000x reference)
//
#include <hip/hip_runtime.h>

#define DIM 4096
using F2 = float2;

// R16: 4 WAVES PER STATE (256 threads, 16 amps/lane). R14/R15 post-mortem:
// occupancy is GRID-capped (2048 blocks), not resource-capped. R14 = 4
// waves/SIMD supplied -> VALUBusy 51%; R15 = 2 -> 39%. Fix: quadruple wave
// count per state: 2048 blocks x 4 waves = 8 waves/SIMD supplied.
// 4-bit register windows, 6 transposes: A{0-3} B{3-6} C{6-9} D{9,10,11,0}
// then D->C'->B'->A' (layer-1 reversed ring). 4 of 6 transposes are
// WAVE-INTERNAL (wave bits identical on both sides and absent from both reg
// sets): T1,T2,T4,T6 -> no barriers, same-wave lgkmcnt fence only (DS ops of
// one wave are processed in order). T3,T5 move data across waves -> real
// __syncthreads. 8 block-barriers total (R14 had 18).
//
// Address bits: qubit q <-> a[11-q]. Layouts (reg bit value in parens):
//  A : regs a11(8) a10(4) a9(2) a8(1); lanes a7..a2=l5..l0; wave a1a0
//      masks: q0:8 q1:4 q2:2 q3:1
//  B : regs a8(1) a7(4) a6(8) a5(2); lanes a11,a10,a9,a4,a3,a2=l5..l0; wave a1a0
//      masks: q3:1 q4:4 q5:8 q6:2
//  C : regs a5(2) a4(4) a3(8) a2(1); lanes a11..a6=l5..l0; wave a1a0
//      masks: q6:2 q7:4 q8:8 q9:1
//  D : regs a2(1) a1(2) a0(4) a11(8); lanes a10,a9,a8,a5,a4,a3=l5..l0; wave a7a6
//      masks: q9:1 q10:2 q11:4 q0:8
//  C': regs as C; lanes a11,a10,a9,a8,a1,a0=l5..l0; wave a7a6
//  B': = B.   A': = A.
// Transitions (shared qubit's addr bit deleted; 2048-F2 = 16 KB buffer,
// halves split on the shared REG bit, same bit both sides):
//  T1 A->B  del a8 (q3)  SB=1  internal (wave a1a0 both)
//  T2 B->C  del a5 (q6)  SB=2  internal
//  T3 C->D  del a2 (q9)  SB=1  CROSS (a1a0 -> a7a6)
//  T4 D->C' del a2 (q9)  SB=1  internal (wave a7a6 both)
//  T5 C'->B' del a5 (q6) SB=2  CROSS (a7a6 -> a1a0)
//  T6 B'->A' del a8 (q3) SB=1  internal
// Buffer packings (physical index f10..f0) put the relevant wave bits at
// f10,f9 so consecutive transposes are physically wave-disjoint (no barrier
// at T1-T2, T3-T4, T4-T5 boundaries); f3..f0 are XOR mixes chosen so every
// ST/LD pattern covers 16 bank-pairs x 4 lanes, 2-way (free) per 32-lane
// half (except T3-ST: 4-way/half, structural). All packings bijective;
// cross-side identity spot-checked per transition (see formulas below).

// ---- packed fp32 complex primitives (VOP3P) — proven R8-R15 ----
__device__ __forceinline__ F2 pk_mul_bl(F2 a, F2 u) {   // (a.x*u.x, a.y*u.x)
    F2 d;
    asm("v_pk_mul_f32 %0, %1, %2 op_sel:[0,0] op_sel_hi:[1,0]"
        : "=v"(d) : "v"(a), "v"(u));
    return d;
}
__device__ __forceinline__ void pk_cross(F2& d, F2 a, F2 u) {  // d += (-a.y*u.y, a.x*u.y)
    asm("v_pk_fma_f32 %0, %1, %2, %0 op_sel:[1,1,0] op_sel_hi:[0,1,1] neg_lo:[1,0,0]"
        : "+v"(d) : "v"(a), "v"(u));
}
__device__ __forceinline__ void pk_fma_bl(F2& d, F2 a, F2 u) { // d += (a.x*u.x, a.y*u.x)
    asm("v_pk_fma_f32 %0, %1, %2, %0 op_sel:[0,0,0] op_sel_hi:[1,0,1]"
        : "+v"(d) : "v"(a), "v"(u));
}
__device__ __forceinline__ void pk_swapneg(F2& d, F2 a, F2 cs) { // d += (a.y*cs.y, -a.x*cs.y)
    asm("v_pk_fma_f32 %0, %1, %2, %0 op_sel:[1,1,0] op_sel_hi:[0,1,1] neg_hi:[1,0,0]"
        : "+v"(d) : "v"(a), "v"(cs));
}
__device__ __forceinline__ void pk_fma(F2& d, F2 a, F2 b) {    // d += a*b
    asm("v_pk_fma_f32 %0, %1, %2, %0" : "+v"(d) : "v"(a), "v"(b));
}
__device__ __forceinline__ void pk_imacc(F2& d, F2 a0, F2 a1) { // d += (a0.x*a1.y, -a0.y*a1.x)
    asm("v_pk_fma_f32 %0, %1, %2, %0 op_sel:[0,1,0] op_sel_hi:[1,0,1] neg_hi:[1,0,0]"
        : "+v"(d) : "v"(a0), "v"(a1));
}
__device__ __forceinline__ F2 pk_cmul(F2 u, F2 a) {
    F2 d = pk_mul_bl(a, u);
    pk_cross(d, a, u);
    return d;
}
__device__ __forceinline__ void pk_cfma(F2& d, F2 u, F2 a) {
    pk_fma_bl(d, a, u);
    pk_cross(d, a, u);
}

__device__ __forceinline__ void build_u(float tx, float ty, float tz, float* u) {
    float sx = sinf(0.5f*tx), cx = cosf(0.5f*tx);
    float sy = sinf(0.5f*ty), cy = cosf(0.5f*ty);
    float sz = sinf(0.5f*tz), cz = cosf(0.5f*tz);
    float A00r = cy*cx, A00i =  sy*sx;     // A = Ry*Rx
    float A01r = -sy*cx, A01i = -cy*sx;
    float A10r =  sy*cx, A10i = -cy*sx;
    float A11r =  cy*cx, A11i = -sy*sx;
    // U = Rz*A: row0 *= (cz - i sz), row1 *= (cz + i sz)   [verified r1/3/5..15]
    u[0] = cz*A00r + sz*A00i;  u[1] = cz*A00i - sz*A00r;
    u[2] = cz*A01r + sz*A01i;  u[3] = cz*A01i - sz*A01r;
    u[4] = cz*A10r - sz*A10i;  u[5] = cz*A10i + sz*A10r;
    u[6] = cz*A11r - sz*A11i;  u[7] = cz*A11i + sz*A11r;
}

// coef layout (floats): [0..95] U0 plain (q*8); [96..191] RX(ang[36+q-1])*U0[q] (q=1..11);
// [192..287] U1 plain; [288..295] U1[0]*RX(ang[47]); [296..319] L1 CRX (cos,sin)[c=0..11]
__global__ void prep_kernel(const float* __restrict__ ang, float* __restrict__ coef) {
    int t = threadIdx.x;
    if (t < 12) {
        float u[8]; build_u(ang[t], ang[12+t], ang[24+t], u);
#pragma unroll
        for (int j = 0; j < 8; ++j) coef[t*8 + j] = u[j];
    } else if (t < 24) {
        int q = t - 12;
        float u[8]; build_u(ang[48+q], ang[60+q], ang[72+q], u);
#pragma unroll
        for (int j = 0; j < 8; ++j) coef[192 + q*8 + j] = u[j];
    } else if (t < 36) {
        int c = t - 24;
        float th = 0.5f * ang[95 - c];     // L1 ring gate (c,c+1) = tape slot 84+(11-c)
        coef[296 + c*2]     = cosf(th);
        coef[296 + c*2 + 1] = sinf(th);
    } else if (t < 47) {
        int q = t - 35;                    // 1..11: M = RX(ang[36+q-1]) * U0[q]
        float u[8]; build_u(ang[q], ang[12+q], ang[24+q], u);
        float c = cosf(0.5f*ang[36+q-1]), s = sinf(0.5f*ang[36+q-1]);
        float m[8];
        m[0] = c*u[0] + s*u[5];  m[1] = c*u[1] - s*u[4];   // M00 = c u00 - i s u10
        m[2] = c*u[2] + s*u[7];  m[3] = c*u[3] - s*u[6];   // M01 = c u01 - i s u11
        m[4] = s*u[1] + c*u[4];  m[5] = -s*u[0] + c*u[5];  // M10 = -i s u00 + c u10
        m[6] = s*u[3] + c*u[6];  m[7] = -s*u[2] + c*u[7];  // M11 = -i s u01 + c u11
#pragma unroll
        for (int j = 0; j < 8; ++j) coef[96 + q*8 + j] = m[j];
    } else if (t == 47) {                  // M = U1[0] * RX(ang[47])  [CR0(11,0) then U1(0)]
        float u[8]; build_u(ang[48], ang[60], ang[72], u);
        float c = cosf(0.5f*ang[47]), s = sinf(0.5f*ang[47]);
        float m[8];
        m[0] = c*u[0] + s*u[3];  m[1] = c*u[1] - s*u[2];   // M00 = c u00 - i s u01
        m[2] = s*u[1] + c*u[2];  m[3] = -s*u[0] + c*u[3];  // M01 = -i s u00 + c u01
        m[4] = c*u[4] + s*u[7];  m[5] = c*u[5] - s*u[6];   // M10 = c u10 - i s u11
        m[6] = s*u[5] + c*u[6];  m[7] = -s*u[4] + c*u[7];  // M11 = -i s u10 + c u11
#pragma unroll
        for (int j = 0; j < 8; ++j) coef[288 + j] = m[j];
    }
}

// ---- register-part (compile-time per unrolled r) of each packing ----
__device__ __forceinline__ int rpA1(int r) {   // T1/T6, A side (a8 deleted = r&1)
    int a11=(r>>3)&1, a10=(r>>2)&1, a9=(r>>1)&1;
    return (a11<<8)|(a10<<7)|(a9<<6)|(a11<<3)|(a10<<2)|(a9<<1)|(a9<<0);
}
__device__ __forceinline__ int rpB1(int r) {   // T1/T6, B side
    int a5=(r>>1)&1, a7=(r>>2)&1, a6=(r>>3)&1;
    return (a7<<5)|(a6<<4)|(a7<<3)|(a6<<2)|(a5<<0);
}
__device__ __forceinline__ int rpB2(int r) {   // T2, B side (a5 deleted = r&2)
    int a8=r&1, a7=(r>>2)&1, a6=(r>>3)&1;
    return (a8<<5)|(a7<<4)|(a6<<3)|(a7<<2)|(a8<<1)|(a6<<0);
}
__device__ __forceinline__ int rpC2(int r) {   // T2, C side
    int a2=r&1, a4=(r>>2)&1, a3=(r>>3)&1;
    return (a3<<3)|(a2<<2)|(a4<<1);
}
__device__ __forceinline__ int rpC3(int r) {   // T3/T4, C/C' side (a2 deleted = r&1)
    int a5=(r>>1)&1, a4=(r>>2)&1, a3=(r>>3)&1;
    return (a5<<4)|(a3<<3)|(a4<<2)|(a5<<0);
}
__device__ __forceinline__ int rpD3(int r) {   // T3/T4, D side
    int a1=(r>>1)&1, a0=(r>>2)&1, a11=(r>>3)&1;
    return (a11<<8)|(a11<<3)|(a1<<1)|((a0^a11)<<0);
}
__device__ __forceinline__ int rpC5(int r) {   // T5, C' side (a5 deleted = r&2)
    int a2=r&1, a4=(r>>2)&1, a3=(r>>3)&1;
    return (a4<<4)|(a3<<3)|(a2<<2)|(a4<<0);
}
__device__ __forceinline__ int rpB5(int r) {   // T5, B' side
    int a8=r&1, a7=(r>>2)&1, a6=(r>>3)&1;
    return (a7<<10)|(a6<<9)|(a8<<5)|(a8<<3);
}

// SB != 0 restricts to pairs with (r0 & SB) == HB (half-gates filling
// transpose windows). SB is never equal to M.
template<int M, int SB, int HB>
__device__ __forceinline__ void g1q(F2* amp, const float* __restrict__ u) {
    F2 u00 = {u[0], u[1]}, u01 = {u[2], u[3]};
    F2 u10 = {u[4], u[5]}, u11 = {u[6], u[7]};
#pragma unroll
    for (int r0 = 0; r0 < 16; ++r0) {
        if (r0 & M) continue;
        if (SB != 0 && (r0 & SB) != HB) continue;
        const int r1 = r0 + M;
        F2 a0 = amp[r0], a1 = amp[r1];
        F2 n0 = pk_cmul(u00, a0); pk_cfma(n0, u01, a1);
        F2 n1 = pk_cmul(u10, a0); pk_cfma(n1, u11, a1);
        amp[r0] = n0; amp[r1] = n1;
    }
}

template<int MSEL, int M, int SB, int HB>   // matrix selected by control bit MSEL
__device__ __forceinline__ void fg1q(F2* amp, const float* __restrict__ uA,
                                     const float* __restrict__ uB) {
    F2 a00 = {uA[0], uA[1]}, a01 = {uA[2], uA[3]}, a10 = {uA[4], uA[5]}, a11 = {uA[6], uA[7]};
    F2 b00 = {uB[0], uB[1]}, b01 = {uB[2], uB[3]}, b10 = {uB[4], uB[5]}, b11 = {uB[6], uB[7]};
#pragma unroll
    for (int r0 = 0; r0 < 16; ++r0) {
        if (r0 & M) continue;
        if (SB != 0 && (r0 & SB) != HB) continue;
        const int r1 = r0 + M;
        const bool sel = (r0 & MSEL) != 0;           // compile-time
        F2 u00 = sel ? b00 : a00, u01 = sel ? b01 : a01;
        F2 u10 = sel ? b10 : a10, u11 = sel ? b11 : a11;
        F2 a0 = amp[r0], a1 = amp[r1];
        F2 n0 = pk_cmul(u00, a0); pk_cfma(n0, u01, a1);
        F2 n1 = pk_cmul(u10, a0); pk_cfma(n1, u11, a1);
        amp[r0] = n0; amp[r1] = n1;
    }
}

template<int MC, int MT>
__device__ __forceinline__ void crx(F2* amp, F2 cs) {
#pragma unroll
    for (int r0 = 0; r0 < 16; ++r0) {
        if (!(r0 & MC) || (r0 & MT)) continue;
        const int r1 = r0 + MT;
        F2 a0 = amp[r0], a1 = amp[r1];
        F2 n0 = pk_mul_bl(a0, cs); pk_swapneg(n0, a1, cs);
        F2 n1 = pk_mul_bl(a1, cs); pk_swapneg(n1, a0, cs);
        amp[r0] = n0; amp[r1] = n1;
    }
}

template<int M>
__device__ __forceinline__ void expv(const F2* amp, int q, int lane,
                                     float& fx, float& fy, float& fz) {
    F2 zp = {0.f, 0.f}, zm = {0.f, 0.f}, xp = {0.f, 0.f}, ip = {0.f, 0.f};
#pragma unroll
    for (int r0 = 0; r0 < 16; ++r0) {
        if (r0 & M) continue;
        const int r1 = r0 + M;
        F2 a0 = amp[r0], a1 = amp[r1];
        pk_fma(zp, a0, a0);
        pk_fma(zm, a1, a1);
        pk_fma(xp, a0, a1);
        pk_imacc(ip, a0, a1);
    }
    float zz = (zp.x + zp.y) - (zm.x + zm.y);
    float xr = 2.f * (xp.x + xp.y);
    float xi = 2.f * (ip.x + ip.y);
#pragma unroll
    for (int off = 32; off; off >>= 1) {
        xr += __shfl_xor(xr, off);
        xi += __shfl_xor(xi, off);
        zz += __shfl_xor(zz, off);
    }
    if (lane == q) { fx = xr; fy = xi; fz = zz; }
}

// enumerate j-th pair base r0 with (r0 & M)==0 and (r0 & SB)==hb*SB (4-bit regs)
template<int M, int SB>
__device__ __forceinline__ int r0_of(int j, int hb) {
    int r = hb ? SB : 0, b = 1;
#pragma unroll
    for (int p = 0; p < 4; ++p) {
        const int mm = 1 << p;
        if (mm == M || mm == SB) continue;
        if (j & b) r |= mm;
        b <<= 1;
    }
    return r;
}

// Store one half (8 regs with (r & SB) == HB).
#define ST_T(TP, RP, SB, HB) \
  { _Pragma("unroll") for (int r = 0; r < 16; ++r) { \
      if ((r & (SB)) != (HB)) continue; \
      psi[(TP) ^ RP(r)] = amp[r]; } }
// Load one half in pair order of the next gate (mask M).
#define LD_T(TP, RP, M, SB, HB) \
  { _Pragma("unroll") for (int k = 0; k < 8; ++k) { \
      const int j = k >> 1; \
      const int r0 = r0_of<M, SB>(j, (HB) != 0); \
      const int r = (k & 1) ? (r0 + (M)) : r0; \
      amp[r] = psi[(TP) ^ RP(r)]; } }

// same-wave DS drain: guarantees this wave's prior LDS writes/reads are
// complete before its next LDS ops reuse the buffer (wave-internal
// transposes; DS ops of one wave are processed in order — fence is insurance)
#define WAVE_FENCE asm volatile("s_waitcnt lgkmcnt(0)" ::: "memory")

#define U0P(q, M)               g1q<M, 0, 0>(amp, cf + (q)*8)
#define FU0(q, MS, M)           fg1q<MS, M, 0, 0>(amp, cf + (q)*8, cf + 96 + (q)*8)
#define FU0_H(q, MS, M, SB, HB) fg1q<MS, M, SB, HB>(amp, cf + (q)*8, cf + 96 + (q)*8)
#define U1P(q, M)               g1q<M, 0, 0>(amp, cf + 192 + (q)*8)
#define U1P_H(q, M, SB, HB)     g1q<M, SB, HB>(amp, cf + 192 + (q)*8)
#define FU1_0()                 fg1q<4, 8, 0, 0>(amp, cf + 192, cf + 288)
#define CR1(c, MC, MT)          crx<MC, MT>(amp, F2{cf[296 + (c)*2], cf[296 + (c)*2 + 1]})
#define EXPV(q, M)              expv<M>(amp, q, l, fx, fy, fz)

__global__ __launch_bounds__(256, 6)
void qsim_kernel(const float* __restrict__ sv,      // [B, 4096]
                 const float* __restrict__ cf,      // [320] precomputed coefficients
                 const float* __restrict__ W,       // [10, 36]
                 const float* __restrict__ bvec,    // [10]
                 float* __restrict__ out)           // [B, 10]
{
    __shared__ F2 psi[2048];         // 16 KB split-transpose buffer
    const int t = threadIdx.x;
    const int b = blockIdx.x;
    const int l = t & 63, w = t >> 6;
    const int w1 = (w >> 1) & 1, w0 = w & 1;
    const int l0 = l & 1, l1 = (l >> 1) & 1, l2 = (l >> 2) & 1;
    const int l3 = (l >> 3) & 1, l4 = (l >> 4) & 1, l5 = (l >> 5) & 1;

    F2 amp[16];
    const float* svb = sv + (size_t)b * DIM;
    // layout A: idx = r<<8 | l<<2 | w; pair order for U0P(0, M=8)
#pragma unroll
    for (int k = 0; k < 16; ++k) {
        const int r = (k & 1) ? ((k >> 1) + 8) : (k >> 1);
        amp[r] = make_float2(svb[(r << 8) | (l << 2) | w], 0.f);
    }

    float fx = 0.f, fy = 0.f, fz = 0.f;

    // ---- A {q0:8 q1:4 q2:2 q3:1}: U0(0); [U0;CR0] q=1..3 ----
    U0P(0, 8);
    FU0(1, 8, 4); FU0(2, 4, 2); FU0(3, 2, 1);

    // ---- T1 A->B (internal, del a8, SB=1): halfgate FU0(4,1,4) ----
    {
        const int tpA = (w1<<10)|(w0<<9)|(l5<<5)|(l4<<4)|((l1^l5)<<3)|((l0^l4)<<2)|(l2<<1)|(l3<<0);
        const int tpB = (w1<<10)|(w0<<9)|(l5<<8)|(l4<<7)|(l3<<6)|((l1^l5)<<3)|((l0^l4)<<2)|((l2^l3)<<1)|(l3<<0);
        ST_T(tpA, rpA1, 1, 0); WAVE_FENCE;
        LD_T(tpB, rpB1, 4, 1, 0); WAVE_FENCE;
        ST_T(tpA, rpA1, 1, 1);
        FU0_H(4, 1, 4, 1, 0);
        WAVE_FENCE;
        LD_T(tpB, rpB1, 4, 1, 1);
        FU0_H(4, 1, 4, 1, 1);
    }
    // ---- B {q3:1 q4:4 q5:8 q6:2} ----
    FU0(5, 4, 8); FU0(6, 8, 2);

    // ---- T2 B->C (internal, del a5, SB=2): halfgate FU0(7,2,4) ----
    {
        const int tpB = (w1<<10)|(w0<<9)|(l5<<8)|(l4<<7)|(l3<<6)|((l1^l5)<<3)|((l0^l4)<<2)|((l2^l3)<<1)|(l3<<0);
        const int tpC = (w1<<10)|(w0<<9)|(l5<<8)|(l4<<7)|(l3<<6)|(l2<<5)|(l1<<4)|((l5^l0)<<3)|((l4^l1)<<2)|((l3^l2)<<1)|((l0^l3)<<0);
        ST_T(tpB, rpB2, 2, 0); WAVE_FENCE;
        LD_T(tpC, rpC2, 4, 2, 0); WAVE_FENCE;
        ST_T(tpB, rpB2, 2, 2);
        FU0_H(7, 2, 4, 2, 0);
        WAVE_FENCE;
        LD_T(tpC, rpC2, 4, 2, 2);
        FU0_H(7, 2, 4, 2, 2);
    }
    // ---- C {q6:2 q7:4 q8:8 q9:1} ----
    FU0(8, 4, 8); FU0(9, 8, 1);

    // ---- T3 C->D (CROSS, del a2, SB=1): halfgate FU0(10,1,2) ----
    __syncthreads();                 // T2 slots not wave-disjoint vs T3 stores
    {
        const int tpC = (l1<<10)|(l0<<9)|(l5<<8)|(l4<<7)|(l3<<6)|(l2<<5)|((l5^l4)<<3)|(l3<<2)|((w1^l2)<<1)|((w0^l5)<<0);
        const int tpD = (w1<<10)|(w0<<9)|(l5<<7)|(l4<<6)|(l3<<5)|(l2<<4)|((l0^l5)<<3)|((l1^l4)<<2)|(l3<<1)|(l2<<0);
        ST_T(tpC, rpC3, 1, 0);
        __syncthreads();
        LD_T(tpD, rpD3, 2, 1, 0);
        __syncthreads();
        ST_T(tpC, rpC3, 1, 1);
        FU0_H(10, 1, 2, 1, 0);
        __syncthreads();
        LD_T(tpD, rpD3, 2, 1, 1);
        FU0_H(10, 1, 2, 1, 1);
    }
    // ---- D {q9:1 q10:2 q11:4 q0:8}: [CR0(11,0);U1(0)]; U1(9..11);
    //      L1 ring (11,0),(10,11),(9,10); expv 10,11 ----
    FU0(11, 2, 4);
    FU1_0();
    U1P(9, 1); U1P(10, 2); U1P(11, 4);
    CR1(11, 4, 8); CR1(10, 2, 4); CR1(9, 1, 2);
    EXPV(10, 2); EXPV(11, 4);

    // ---- T4 D->C' (internal, del a2, SB=1): halfgate U1P(7,4) ----
    // no barrier: T3-LD and T4-ST slots both carry a7a6=wave at f10,f9
    {
        const int tpD = (w1<<10)|(w0<<9)|(l5<<7)|(l4<<6)|(l3<<5)|(l2<<4)|((l0^l5)<<3)|((l1^l4)<<2)|(l3<<1)|(l2<<0);
        const int tpC = (w1<<10)|(w0<<9)|(l5<<8)|(l4<<7)|(l3<<6)|(l2<<5)|((l5^l4)<<3)|(l3<<2)|((l1^l2)<<1)|((l0^l5)<<0);
        ST_T(tpD, rpD3, 1, 0); WAVE_FENCE;
        LD_T(tpC, rpC3, 4, 1, 0); WAVE_FENCE;
        ST_T(tpD, rpD3, 1, 1);
        U1P_H(7, 4, 1, 0);
        WAVE_FENCE;
        LD_T(tpC, rpC3, 4, 1, 1);
        U1P_H(7, 4, 1, 1);
    }
    // ---- C' {q6:2 q7:4 q8:8 q9:1}: U1(6,8); ring (8,9),(7,8),(6,7); expv 7,8,9 ----
    U1P(6, 2); U1P(8, 8);
    CR1(8, 8, 1); CR1(7, 4, 8); CR1(6, 2, 4);
    EXPV(9, 1); EXPV(8, 8); EXPV(7, 4);

    // ---- T5 C'->B' (CROSS, del a5, SB=2): halfgate U1P(3,1) ----
    // no leading barrier: T4-LD and T5-ST slots both carry a7a6=wave at f10,f9
    {
        const int tpC = (w1<<10)|(w0<<9)|(l5<<8)|(l4<<7)|(l3<<6)|(l2<<5)|((l5^l2)<<3)|(l4<<2)|((l1^l3)<<1)|(l0<<0);
        const int tpB = (l5<<8)|(l4<<7)|(l3<<6)|(l2<<4)|((l1^l5)<<3)|((l0^l4)<<2)|((w1^l3)<<1)|((w0^l2)<<0);
        ST_T(tpC, rpC5, 2, 0);
        __syncthreads();
        LD_T(tpB, rpB5, 1, 2, 0);
        __syncthreads();
        ST_T(tpC, rpC5, 2, 2);
        U1P_H(3, 1, 2, 0);
        __syncthreads();
        LD_T(tpB, rpB5, 1, 2, 2);
        U1P_H(3, 1, 2, 2);
        __syncthreads();             // protect cross-wave reads from T6 stores
    }
    // ---- B' {q3:1 q4:4 q5:8 q6:2}: U1(4,5); ring (5,6),(4,5),(3,4); expv 4,5,6 ----
    U1P(4, 4); U1P(5, 8);
    CR1(5, 8, 2); CR1(4, 4, 8); CR1(3, 1, 4);
    EXPV(6, 2); EXPV(5, 8); EXPV(4, 4);

    // ---- T6 B'->A' (internal, del a8, SB=1): halfgate U1P(1,4) ----
    {
        const int tpB = (w1<<10)|(w0<<9)|(l5<<8)|(l4<<7)|(l3<<6)|((l1^l5)<<3)|((l0^l4)<<2)|((l2^l3)<<1)|(l3<<0);
        const int tpA = (w1<<10)|(w0<<9)|(l5<<5)|(l4<<4)|((l1^l5)<<3)|((l0^l4)<<2)|(l2<<1)|(l3<<0);
        ST_T(tpB, rpB1, 1, 0); WAVE_FENCE;
        LD_T(tpA, rpA1, 4, 1, 0); WAVE_FENCE;
        ST_T(tpB, rpB1, 1, 1);
        U1P_H(1, 4, 1, 0);
        WAVE_FENCE;
        LD_T(tpA, rpA1, 4, 1, 1);
        U1P_H(1, 4, 1, 1);
    }
    // ---- A' {q0:8 q1:4 q2:2 q3:1}: U1(2); ring (2,3),(1,2),(0,1); expv 0..3 ----
    U1P(2, 2);
    CR1(2, 2, 1); CR1(1, 4, 2); CR1(0, 8, 4);
    EXPV(3, 1); EXPV(2, 2); EXPV(1, 4); EXPV(0, 8);

    // ---- combine 4 waves' partial features ----
    __syncthreads();                 // psi dead only after all waves' T6 loads
    float* fbuf = (float*)psi;       // [4][36]
    if (l < 12) {
        fbuf[w * 36 + l]      = fx;
        fbuf[w * 36 + 12 + l] = fy;
        fbuf[w * 36 + 24 + l] = fz;
    }
    __syncthreads();
    if (t < 10) {
        float a = bvec[t];
#pragma unroll
        for (int f = 0; f < 36; ++f)
            a += W[t * 36 + f] * (fbuf[f] + fbuf[36 + f] + fbuf[72 + f] + fbuf[108 + f]);
        out[(size_t)b * 10 + t] = a;
    }
}

extern "C" void kernel_launch(void* const* d_in, const int* in_sizes, int n_in,
                              void* d_out, int out_size, void* d_ws, size_t ws_size,
                              hipStream_t stream) {
    const float* sv     = (const float*)d_in[0];
    const float* angles = (const float*)d_in[1];
    const float* W      = (const float*)d_in[2];
    const float* bvec   = (const float*)d_in[3];
    float* out  = (float*)d_out;
    float* coef = (float*)d_ws;      // 320 floats of scratch
    int batch = in_sizes[0] / DIM;   // 2048
    prep_kernel<<<1, 64, 0, stream>>>(angles, coef);
    qsim_kernel<<<batch, 256, 0, stream>>>(sv, coef, W, bvec, out);
}